// Round 1
// baseline (3846.903 us; speedup 1.0000x reference)
//
#include <hip/hip_runtime.h>
#include <math.h>

#define NA   20000
#define PE   320000
#define FDIM 128
#define RDIM 64
#define MDIM 32
#define DX   448      // x_inv feature dim
#define XS   452      // padded LDS stride for x tile (452 % 32 == 4 -> conflict-free)
#define HS   132      // padded stride for 128-wide LDS tiles
#define ET   32       // edges per tile
#define AT   32       // atoms per tile

__device__ __forceinline__ float silu_f(float z) {
    return z / (1.0f + __expf(-z));
}

__device__ __forceinline__ void fma_4k(float (&acc)[4], const float4 xv,
                                       const float4 w0, const float4 w1,
                                       const float4 w2, const float4 w3) {
    acc[0] = fmaf(xv.x, w0.x, fmaf(xv.y, w1.x, fmaf(xv.z, w2.x, fmaf(xv.w, w3.x, acc[0]))));
    acc[1] = fmaf(xv.x, w0.y, fmaf(xv.y, w1.y, fmaf(xv.z, w2.y, fmaf(xv.w, w3.y, acc[1]))));
    acc[2] = fmaf(xv.x, w0.z, fmaf(xv.y, w1.z, fmaf(xv.z, w2.z, fmaf(xv.w, w3.z, acc[2]))));
    acc[3] = fmaf(xv.x, w0.w, fmaf(xv.y, w1.w, fmaf(xv.z, w2.w, fmaf(xv.w, w3.w, acc[3]))));
}

// ---------------------------------------------------------------------------
// Fused per-edge kernel: builds x_inv tile in LDS, runs the eq MLP (-> g) and
// inv MLP (-> m), computes dv inline, and scatter-adds via sorted-run scan.
// Reads OLD s,v; atomically accumulates into s_out / v_out (pre-copied).
// ---------------------------------------------------------------------------
__global__ __launch_bounds__(256, 2)
void edge_kernel(const float* __restrict__ rbfs,
                 const float* __restrict__ dists,
                 const float* __restrict__ vecs,
                 const float* __restrict__ cuts,
                 const int*   __restrict__ gidx_i,
                 const int*   __restrict__ gidx_j,
                 const float* __restrict__ s_in,
                 const float* __restrict__ v_in,
                 const float* __restrict__ Wrbf,   // 320 x 32
                 const float* __restrict__ W1eq,   // 448 x 128 (padded for b=0)
                 const float* __restrict__ b1eq,   // 128
                 const float* __restrict__ W2eq,   // 128 x 64
                 const float* __restrict__ W1inv,  // 448 x 128
                 const float* __restrict__ b1inv,  // 128
                 const float* __restrict__ W2inv,  // 128 x 128
                 const float* __restrict__ b2inv,  // 128
                 float* __restrict__ s_out,
                 float* __restrict__ v_out,
                 const int eqSkip)                 // 1: skip x rows [32,192) in eq GEMM (block 0)
{
    // x layout: [e(32) | a_ui(32) | a_uj(32) | a_ij(32) | a_ii(32) | a_jj(32) | si(128) | sj(128)]
    __shared__ float xs[ET][XS];
    __shared__ float hb[ET][HS];   // h1_eq; later g (cols 0..63)
    __shared__ float us[ET][4];    // ux,uy,uz,cutoff
    __shared__ int   iis[ET + 1];
    __shared__ int   jjs[ET];

    const int t  = threadIdx.x;
    const int p0 = blockIdx.x * ET;

    // ---------- stage: si/sj -> xs, u/cutoff, indices ----------
    {
        const int e = t >> 3, l = t & 7;
        const int p = p0 + e;
        const int i = gidx_i[p];
        const int j = gidx_j[p];
        const float4* si4 = (const float4*)(s_in + (size_t)i * FDIM);
        const float4* sj4 = (const float4*)(s_in + (size_t)j * FDIM);
        #pragma unroll
        for (int q = 0; q < 4; q++) {
            const int c4 = l + 8 * q;
            *(float4*)&xs[e][192 + 4 * c4] = si4[c4];
            *(float4*)&xs[e][320 + 4 * c4] = sj4[c4];
        }
        if (t < ET) {
            const int pp = p0 + t;
            const float dinv = 1.0f / (dists[pp] + 0.001f);
            us[t][0] = vecs[pp * 3 + 0] * dinv;
            us[t][1] = vecs[pp * 3 + 1] * dinv;
            us[t][2] = vecs[pp * 3 + 2] * dinv;
            us[t][3] = cuts[pp];
            jjs[t] = gidx_j[pp];
        }
        if (t < ET + 1) {
            const int pp = p0 + t;
            iis[t] = (pp < PE) ? gidx_i[pp] : -1;
        }
    }
    __syncthreads();

    // ---------- a_* terms -> xs cols [32,192) ----------
    {
        const int e  = t >> 3;
        const int m0 = (t & 7) * 4;
        const int i = iis[e];
        const int j = jjs[e];
        float vi[3][4], vj[3][4];
        #pragma unroll
        for (int d = 0; d < 3; d++) {
            const float4 a = *(const float4*)(v_in + (size_t)i * 96 + d * MDIM + m0);
            const float4 b = *(const float4*)(v_in + (size_t)j * 96 + d * MDIM + m0);
            vi[d][0] = a.x; vi[d][1] = a.y; vi[d][2] = a.z; vi[d][3] = a.w;
            vj[d][0] = b.x; vj[d][1] = b.y; vj[d][2] = b.z; vj[d][3] = b.w;
        }
        const float ux = us[e][0], uy = us[e][1], uz = us[e][2];
        float aui[4], auj[4], aij[4], aii[4], ajj[4];
        #pragma unroll
        for (int mm = 0; mm < 4; mm++) {
            aui[mm] = ux * vi[0][mm] + uy * vi[1][mm] + uz * vi[2][mm];
            auj[mm] = ux * vj[0][mm] + uy * vj[1][mm] + uz * vj[2][mm];
            aij[mm] = vi[0][mm] * vj[0][mm] + vi[1][mm] * vj[1][mm] + vi[2][mm] * vj[2][mm];
            aii[mm] = vi[0][mm] * vi[0][mm] + vi[1][mm] * vi[1][mm] + vi[2][mm] * vi[2][mm];
            ajj[mm] = vj[0][mm] * vj[0][mm] + vj[1][mm] * vj[1][mm] + vj[2][mm] * vj[2][mm];
        }
        *(float4*)&xs[e][ 32 + m0] = make_float4(aui[0], aui[1], aui[2], aui[3]);
        *(float4*)&xs[e][ 64 + m0] = make_float4(auj[0], auj[1], auj[2], auj[3]);
        *(float4*)&xs[e][ 96 + m0] = make_float4(aij[0], aij[1], aij[2], aij[3]);
        *(float4*)&xs[e][128 + m0] = make_float4(aii[0], aii[1], aii[2], aii[3]);
        *(float4*)&xs[e][160 + m0] = make_float4(ajj[0], ajj[1], ajj[2], ajj[3]);
    }

    // ---------- e = [rbf | si | sj] @ Wrbf -> xs cols [0,32) ----------
    {
        const int e  = t >> 3;
        const int c0 = (t & 7) * 4;
        float acc[4] = {0.f, 0.f, 0.f, 0.f};
        const float* rb = rbfs + (size_t)(p0 + e) * RDIM;
        for (int k = 0; k < RDIM; k++) {
            const float xv = rb[k];
            const float4 w = *(const float4*)(Wrbf + k * 32 + c0);
            acc[0] = fmaf(xv, w.x, acc[0]);
            acc[1] = fmaf(xv, w.y, acc[1]);
            acc[2] = fmaf(xv, w.z, acc[2]);
            acc[3] = fmaf(xv, w.w, acc[3]);
        }
        for (int k = RDIM; k < 320; k++) {
            const float xv = xs[e][k + 128];   // si/sj live at xs col k+128
            const float4 w = *(const float4*)(Wrbf + k * 32 + c0);
            acc[0] = fmaf(xv, w.x, acc[0]);
            acc[1] = fmaf(xv, w.y, acc[1]);
            acc[2] = fmaf(xv, w.z, acc[2]);
            acc[3] = fmaf(xv, w.w, acc[3]);
        }
        *(float4*)&xs[e][c0] = make_float4(acc[0], acc[1], acc[2], acc[3]);
    }
    __syncthreads();

    const int e0 = (t >> 5) * 4;   // 4-edge group
    const int c0 = (t & 31) * 4;   // 4-col group (128 cols)

    // ---------- GEMM1-eq: h1 = silu(x @ W1eq + b1eq) ----------
    {
        float acc1[4][4];
        const float4 b = *(const float4*)(b1eq + c0);
        #pragma unroll
        for (int ee = 0; ee < 4; ee++) {
            acc1[ee][0] = b.x; acc1[ee][1] = b.y; acc1[ee][2] = b.z; acc1[ee][3] = b.w;
        }
        int klo = 0, khi = eqSkip ? 32 : DX;
        #pragma unroll 1
        for (int pass = 0; pass < 2; pass++) {
            for (int k = klo; k < khi; k += 4) {
                const float4 w0 = *(const float4*)(W1eq + (size_t)(k + 0) * FDIM + c0);
                const float4 w1 = *(const float4*)(W1eq + (size_t)(k + 1) * FDIM + c0);
                const float4 w2 = *(const float4*)(W1eq + (size_t)(k + 2) * FDIM + c0);
                const float4 w3 = *(const float4*)(W1eq + (size_t)(k + 3) * FDIM + c0);
                #pragma unroll
                for (int ee = 0; ee < 4; ee++) {
                    const float4 xv = *(const float4*)&xs[e0 + ee][k];
                    fma_4k(acc1[ee], xv, w0, w1, w2, w3);
                }
            }
            if (!eqSkip) break;
            klo = 192; khi = DX;
        }
        #pragma unroll
        for (int ee = 0; ee < 4; ee++) {
            float4 o;
            o.x = silu_f(acc1[ee][0]); o.y = silu_f(acc1[ee][1]);
            o.z = silu_f(acc1[ee][2]); o.w = silu_f(acc1[ee][3]);
            *(float4*)&hb[e0 + ee][c0] = o;
        }
    }
    __syncthreads();

    // ---------- GEMM2-eq (g, in regs) + GEMM1-inv (in regs) ----------
    float gacc[2][4];
    const int ge0 = (t >> 4) * 2;
    const int gc0 = (t & 15) * 4;
    {
        #pragma unroll
        for (int ee = 0; ee < 2; ee++) {
            gacc[ee][0] = 0.f; gacc[ee][1] = 0.f; gacc[ee][2] = 0.f; gacc[ee][3] = 0.f;
        }
        for (int k = 0; k < FDIM; k += 4) {
            const float4 w0 = *(const float4*)(W2eq + (k + 0) * 64 + gc0);
            const float4 w1 = *(const float4*)(W2eq + (k + 1) * 64 + gc0);
            const float4 w2 = *(const float4*)(W2eq + (k + 2) * 64 + gc0);
            const float4 w3 = *(const float4*)(W2eq + (k + 3) * 64 + gc0);
            #pragma unroll
            for (int ee = 0; ee < 2; ee++) {
                const float4 xv = *(const float4*)&hb[ge0 + ee][k];
                fma_4k(gacc[ee], xv, w0, w1, w2, w3);
            }
        }
    }
    float acc2[4][4];
    {
        const float4 b = *(const float4*)(b1inv + c0);
        #pragma unroll
        for (int ee = 0; ee < 4; ee++) {
            acc2[ee][0] = b.x; acc2[ee][1] = b.y; acc2[ee][2] = b.z; acc2[ee][3] = b.w;
        }
        for (int k = 0; k < DX; k += 4) {
            const float4 w0 = *(const float4*)(W1inv + (size_t)(k + 0) * FDIM + c0);
            const float4 w1 = *(const float4*)(W1inv + (size_t)(k + 1) * FDIM + c0);
            const float4 w2 = *(const float4*)(W1inv + (size_t)(k + 2) * FDIM + c0);
            const float4 w3 = *(const float4*)(W1inv + (size_t)(k + 3) * FDIM + c0);
            #pragma unroll
            for (int ee = 0; ee < 4; ee++) {
                const float4 xv = *(const float4*)&xs[e0 + ee][k];
                fma_4k(acc2[ee], xv, w0, w1, w2, w3);
            }
        }
    }
    __syncthreads();

    // ---------- write g -> hb cols [0,64); silu(h1_inv) -> xs alias ----------
    float* h1i = (float*)xs;   // [ET][HS] alias (xs dead now)
    {
        #pragma unroll
        for (int ee = 0; ee < 2; ee++) {
            *(float4*)&hb[ge0 + ee][gc0] =
                make_float4(gacc[ee][0], gacc[ee][1], gacc[ee][2], gacc[ee][3]);
        }
        #pragma unroll
        for (int ee = 0; ee < 4; ee++) {
            float4 o;
            o.x = silu_f(acc2[ee][0]); o.y = silu_f(acc2[ee][1]);
            o.z = silu_f(acc2[ee][2]); o.w = silu_f(acc2[ee][3]);
            *(float4*)&h1i[(e0 + ee) * HS + c0] = o;
        }
    }
    __syncthreads();

    // ---------- GEMM2-inv: m = silu(h1_inv @ W2inv + b2inv) * cutoff ----------
    float* mb = ((float*)xs) + ET * HS;   // second alias region inside xs
    {
        float acc3[4][4];
        const float4 b = *(const float4*)(b2inv + c0);
        #pragma unroll
        for (int ee = 0; ee < 4; ee++) {
            acc3[ee][0] = b.x; acc3[ee][1] = b.y; acc3[ee][2] = b.z; acc3[ee][3] = b.w;
        }
        for (int k = 0; k < FDIM; k += 4) {
            const float4 w0 = *(const float4*)(W2inv + (size_t)(k + 0) * FDIM + c0);
            const float4 w1 = *(const float4*)(W2inv + (size_t)(k + 1) * FDIM + c0);
            const float4 w2 = *(const float4*)(W2inv + (size_t)(k + 2) * FDIM + c0);
            const float4 w3 = *(const float4*)(W2inv + (size_t)(k + 3) * FDIM + c0);
            #pragma unroll
            for (int ee = 0; ee < 4; ee++) {
                const float4 xv = *(const float4*)&h1i[(e0 + ee) * HS + k];
                fma_4k(acc3[ee], xv, w0, w1, w2, w3);
            }
        }
        #pragma unroll
        for (int ee = 0; ee < 4; ee++) {
            const float cut = us[e0 + ee][3];
            float4 o;
            o.x = silu_f(acc3[ee][0]) * cut; o.y = silu_f(acc3[ee][1]) * cut;
            o.z = silu_f(acc3[ee][2]) * cut; o.w = silu_f(acc3[ee][3]) * cut;
            *(float4*)&mb[(e0 + ee) * HS + c0] = o;
        }
    }
    __syncthreads();

    // ---------- sorted-run scan + scatter (idx_i is sorted) ----------
    if (t < FDIM) {
        // s columns
        float acc = 0.f;
        for (int e = 0; e < ET; e++) {
            acc += mb[e * HS + t];
            if (e == ET - 1 || iis[e + 1] != iis[e]) {
                atomicAdd(&s_out[(size_t)iis[e] * FDIM + t], acc);
                acc = 0.f;
            }
        }
    } else if (t < FDIM + 96) {
        // v columns: col = d*32 + m ; dv computed inline
        const int col = t - FDIM;
        const int d   = col >> 5;
        const int mm  = col & 31;
        float acc = 0.f;
        for (int e = 0; e < ET; e++) {
            const float g0  = hb[e][mm];
            const float g1  = hb[e][MDIM + mm];
            const float vjv = v_in[(size_t)jjs[e] * 96 + col];
            acc = fmaf(us[e][3], fmaf(g0, us[e][d], g1 * vjv), acc);
            if (e == ET - 1 || iis[e + 1] != iis[e]) {
                atomicAdd(&v_out[(size_t)iis[e] * 96 + col], acc);
                acc = 0.f;
            }
        }
    }
}

// ---------------------------------------------------------------------------
// Node update: s += silu(silu([s, s@Wemb] @ W1u + b1u) @ W2u + b2u)
// ---------------------------------------------------------------------------
__global__ __launch_bounds__(256, 2)
void node_kernel(const float* __restrict__ s_in,
                 const float* __restrict__ Wemb,   // 128 x 128
                 const float* __restrict__ W1u,    // 256 x 128
                 const float* __restrict__ b1u,    // 128
                 const float* __restrict__ W2u,    // 128 x 128
                 const float* __restrict__ b2u,    // 128
                 float* __restrict__ s_out)
{
    __shared__ float ss[AT][HS];
    __shared__ float fe[AT][HS];
    __shared__ float t1[AT][HS];
    const int t  = threadIdx.x;
    const int a0 = blockIdx.x * AT;

    {
        const int a = t >> 3, l = t & 7;
        const float4* sr = (const float4*)(s_in + (size_t)(a0 + a) * FDIM);
        #pragma unroll
        for (int q = 0; q < 4; q++) {
            const int c4 = l + 8 * q;
            *(float4*)&ss[a][4 * c4] = sr[c4];
        }
    }
    __syncthreads();

    const int e0 = (t >> 5) * 4;
    const int c0 = (t & 31) * 4;

    // femb = s @ Wemb
    {
        float acc[4][4];
        #pragma unroll
        for (int ee = 0; ee < 4; ee++) {
            acc[ee][0] = 0.f; acc[ee][1] = 0.f; acc[ee][2] = 0.f; acc[ee][3] = 0.f;
        }
        for (int k = 0; k < FDIM; k += 4) {
            const float4 w0 = *(const float4*)(Wemb + (size_t)(k + 0) * FDIM + c0);
            const float4 w1 = *(const float4*)(Wemb + (size_t)(k + 1) * FDIM + c0);
            const float4 w2 = *(const float4*)(Wemb + (size_t)(k + 2) * FDIM + c0);
            const float4 w3 = *(const float4*)(Wemb + (size_t)(k + 3) * FDIM + c0);
            #pragma unroll
            for (int ee = 0; ee < 4; ee++) {
                const float4 xv = *(const float4*)&ss[e0 + ee][k];
                fma_4k(acc[ee], xv, w0, w1, w2, w3);
            }
        }
        #pragma unroll
        for (int ee = 0; ee < 4; ee++) {
            *(float4*)&fe[e0 + ee][c0] =
                make_float4(acc[ee][0], acc[ee][1], acc[ee][2], acc[ee][3]);
        }
    }
    __syncthreads();

    // t1 = silu([s, femb] @ W1u + b1u)
    {
        float acc[4][4];
        const float4 b = *(const float4*)(b1u + c0);
        #pragma unroll
        for (int ee = 0; ee < 4; ee++) {
            acc[ee][0] = b.x; acc[ee][1] = b.y; acc[ee][2] = b.z; acc[ee][3] = b.w;
        }
        for (int k = 0; k < FDIM; k += 4) {
            const float4 w0 = *(const float4*)(W1u + (size_t)(k + 0) * FDIM + c0);
            const float4 w1 = *(const float4*)(W1u + (size_t)(k + 1) * FDIM + c0);
            const float4 w2 = *(const float4*)(W1u + (size_t)(k + 2) * FDIM + c0);
            const float4 w3 = *(const float4*)(W1u + (size_t)(k + 3) * FDIM + c0);
            #pragma unroll
            for (int ee = 0; ee < 4; ee++) {
                const float4 xv = *(const float4*)&ss[e0 + ee][k];
                fma_4k(acc[ee], xv, w0, w1, w2, w3);
            }
        }
        for (int k = 0; k < FDIM; k += 4) {
            const float4 w0 = *(const float4*)(W1u + (size_t)(FDIM + k + 0) * FDIM + c0);
            const float4 w1 = *(const float4*)(W1u + (size_t)(FDIM + k + 1) * FDIM + c0);
            const float4 w2 = *(const float4*)(W1u + (size_t)(FDIM + k + 2) * FDIM + c0);
            const float4 w3 = *(const float4*)(W1u + (size_t)(FDIM + k + 3) * FDIM + c0);
            #pragma unroll
            for (int ee = 0; ee < 4; ee++) {
                const float4 xv = *(const float4*)&fe[e0 + ee][k];
                fma_4k(acc[ee], xv, w0, w1, w2, w3);
            }
        }
        #pragma unroll
        for (int ee = 0; ee < 4; ee++) {
            float4 o;
            o.x = silu_f(acc[ee][0]); o.y = silu_f(acc[ee][1]);
            o.z = silu_f(acc[ee][2]); o.w = silu_f(acc[ee][3]);
            *(float4*)&t1[e0 + ee][c0] = o;
        }
    }
    __syncthreads();

    // s_out = s + silu(t1 @ W2u + b2u)
    {
        float acc[4][4];
        const float4 b = *(const float4*)(b2u + c0);
        #pragma unroll
        for (int ee = 0; ee < 4; ee++) {
            acc[ee][0] = b.x; acc[ee][1] = b.y; acc[ee][2] = b.z; acc[ee][3] = b.w;
        }
        for (int k = 0; k < FDIM; k += 4) {
            const float4 w0 = *(const float4*)(W2u + (size_t)(k + 0) * FDIM + c0);
            const float4 w1 = *(const float4*)(W2u + (size_t)(k + 1) * FDIM + c0);
            const float4 w2 = *(const float4*)(W2u + (size_t)(k + 2) * FDIM + c0);
            const float4 w3 = *(const float4*)(W2u + (size_t)(k + 3) * FDIM + c0);
            #pragma unroll
            for (int ee = 0; ee < 4; ee++) {
                const float4 xv = *(const float4*)&t1[e0 + ee][k];
                fma_4k(acc[ee], xv, w0, w1, w2, w3);
            }
        }
        #pragma unroll
        for (int ee = 0; ee < 4; ee++) {
            float4 o;
            o.x = ss[e0 + ee][c0 + 0] + silu_f(acc[ee][0]);
            o.y = ss[e0 + ee][c0 + 1] + silu_f(acc[ee][1]);
            o.z = ss[e0 + ee][c0 + 2] + silu_f(acc[ee][2]);
            o.w = ss[e0 + ee][c0 + 3] + silu_f(acc[ee][3]);
            *(float4*)(s_out + (size_t)(a0 + e0 + ee) * FDIM + c0) = o;
        }
    }
}

// ---------------------------------------------------------------------------
// Utilities
// ---------------------------------------------------------------------------
__global__ void copyf4(float4* __restrict__ dst, const float4* __restrict__ src, int n4) {
    int i = blockIdx.x * blockDim.x + threadIdx.x;
    const int stride = gridDim.x * blockDim.x;
    for (; i < n4; i += stride) dst[i] = src[i];
}

__global__ void zerof4(float4* __restrict__ dst, int n4) {
    int i = blockIdx.x * blockDim.x + threadIdx.x;
    const int stride = gridDim.x * blockDim.x;
    const float4 z = make_float4(0.f, 0.f, 0.f, 0.f);
    for (; i < n4; i += stride) dst[i] = z;
}

// Pad eq0_W1 (288x128) into 448x128 matching x_inv layout; copy eq1_W1.
__global__ void prep_w1p(const float* __restrict__ eq0,
                         const float* __restrict__ eq1,
                         float* __restrict__ W1p) {
    const int idx = blockIdx.x * blockDim.x + threadIdx.x;
    if (idx < DX * FDIM) {
        const int k = idx >> 7;
        const int c = idx & 127;
        float v0 = 0.f;
        if (k < 32)        v0 = eq0[k * FDIM + c];          // e rows
        else if (k >= 192) v0 = eq0[(k - 160) * FDIM + c];  // si/sj rows
        W1p[idx] = v0;
        W1p[DX * FDIM + idx] = eq1[idx];
    }
}

// ---------------------------------------------------------------------------
extern "C" void kernel_launch(void* const* d_in, const int* in_sizes, int n_in,
                              void* d_out, int out_size, void* d_ws, size_t ws_size,
                              hipStream_t stream) {
    (void)in_sizes; (void)n_in; (void)out_size; (void)ws_size;

    const float* features = (const float*)d_in[0];
    const float* dists    = (const float*)d_in[1];
    const float* vecs     = (const float*)d_in[2];
    const float* cuts     = (const float*)d_in[3];
    const float* rbfs     = (const float*)d_in[4];
    const int*   idx_i    = (const int*)d_in[5];
    const int*   idx_j    = (const int*)d_in[6];
    const float* Wrbf     = (const float*)d_in[7];
    const float* Wemb     = (const float*)d_in[8];
    const float* eq0_W1   = (const float*)d_in[9];
    const float* eq0_b1   = (const float*)d_in[10];
    const float* eq0_W2   = (const float*)d_in[11];
    const float* eq1_W1   = (const float*)d_in[12];
    const float* eq1_b1   = (const float*)d_in[13];
    const float* eq1_W2   = (const float*)d_in[14];
    const float* inv_W1   = (const float*)d_in[15];
    const float* inv_b1   = (const float*)d_in[16];
    const float* inv_W2   = (const float*)d_in[17];
    const float* inv_b2   = (const float*)d_in[18];
    const float* upd_W1   = (const float*)d_in[19];
    const float* upd_b1   = (const float*)d_in[20];
    const float* upd_W2   = (const float*)d_in[21];
    const float* upd_b2   = (const float*)d_in[22];

    float* sA  = (float*)d_ws;
    float* sB  = sA + (size_t)NA * FDIM;
    float* vA  = sB + (size_t)NA * FDIM;
    float* vB  = vA + (size_t)NA * 96;
    float* W1p = vB + (size_t)NA * 96;

    float* s_final = (float*)d_out;
    float* v_final = s_final + (size_t)NA * FDIM;

    const int SN4 = NA * FDIM / 4;
    const int VN4 = NA * 96 / 4;

    prep_w1p<<<(DX * FDIM + 255) / 256, 256, 0, stream>>>(eq0_W1, eq1_W1, W1p);
    copyf4<<<1024, 256, 0, stream>>>((float4*)sA, (const float4*)features, SN4);
    zerof4<<<1024, 256, 0, stream>>>((float4*)vA, VN4);

    // ---- block 0: read (sA, vA) -> accum (sB, vB); node: sB -> sA ----
    copyf4<<<1024, 256, 0, stream>>>((float4*)sB, (const float4*)sA, SN4);
    copyf4<<<1024, 256, 0, stream>>>((float4*)vB, (const float4*)vA, VN4);
    edge_kernel<<<PE / ET, 256, 0, stream>>>(
        rbfs, dists, vecs, cuts, idx_i, idx_j, sA, vA,
        Wrbf, W1p, eq0_b1, eq0_W2,
        inv_W1, inv_b1, inv_W2, inv_b2,
        sB, vB, 1);
    node_kernel<<<NA / AT, 256, 0, stream>>>(sB, Wemb, upd_W1, upd_b1, upd_W2, upd_b2, sA);

    // ---- block 1: read (sA, vB) -> accum (sB, vA); node: sB -> d_out ----
    copyf4<<<1024, 256, 0, stream>>>((float4*)sB, (const float4*)sA, SN4);
    copyf4<<<1024, 256, 0, stream>>>((float4*)vA, (const float4*)vB, VN4);
    edge_kernel<<<PE / ET, 256, 0, stream>>>(
        rbfs, dists, vecs, cuts, idx_i, idx_j, sA, vB,
        Wrbf, W1p + DX * FDIM, eq1_b1, eq1_W2,
        inv_W1 + DX * FDIM, inv_b1 + FDIM, inv_W2 + FDIM * FDIM, inv_b2 + FDIM,
        sB, vA, 0);
    node_kernel<<<NA / AT, 256, 0, stream>>>(
        sB, Wemb, upd_W1 + 2 * FDIM * FDIM, upd_b1 + FDIM,
        upd_W2 + FDIM * FDIM, upd_b2 + FDIM, s_final);

    copyf4<<<1024, 256, 0, stream>>>((float4*)v_final, (const float4*)vA, VN4);
}

// Round 2
// 1031.816 us; speedup vs baseline: 3.7283x; 3.7283x over previous
//
#include <hip/hip_runtime.h>
#include <math.h>

#define NA   20000
#define PE   320000
#define FDIM 128
#define ET   64          // edges per block
#define AT   32          // atoms per tile (node kernel)
#define HS   132         // f32 padded stride (node kernel LDS)

typedef unsigned short ushort_t;
typedef __attribute__((ext_vector_type(8))) short bf16x8;
typedef __attribute__((ext_vector_type(4))) float f32x4;
#define MFMA16 __builtin_amdgcn_mfma_f32_16x16x32_bf16

// LDS byte offsets inside edge_kernel smem
#define XS_OFF   0          // ushort [64][520]  (x tile bf16: e|a*|si|sj|rbf)
#define HBA_OFF  66560      // ushort [64][136]  (h1_eq bf16)
#define HBB_OFF  83968      // ushort [64][136]  (h1_inv bf16)
#define US_OFF   101376     // float  [64][4]    (ux,uy,uz,cut)
#define IIS_OFF  102400     // int    [65]
#define JJS_OFF  102660     // int    [64]
#define SMEM_SZ  102928
#define ML_OFF   0          // float [64][132] alias over xs (m)
#define GL_OFF   33792      // float [64][68]  alias over xs (g)
#define XSTR     520
#define HSTR     136

// packed-weight fragment bases (in frags; 1 frag = 8 ushort = 16B)
#define PK_W1EQ0   0
#define PK_W1EQ1   7168
#define PK_W1INV0  14336
#define PK_W1INV1  21504
#define PK_W2EQ0   28672
#define PK_W2EQ1   29696
#define PK_W2INV0  30720
#define PK_W2INV1  32768
#define PK_WRBF    34816
#define PK_TOTAL   36096

__device__ __forceinline__ float silu_f(float z) {
    return z / (1.0f + __expf(-z));
}

__device__ __forceinline__ ushort_t f2bf(float x) {
    unsigned int u = __float_as_uint(x);
    u = (u + 0x7fffu + ((u >> 16) & 1u)) >> 16;
    return (ushort_t)u;
}

__device__ __forceinline__ unsigned int pack2bf(float x, float y) {
    return (unsigned int)f2bf(x) | ((unsigned int)f2bf(y) << 16);
}

__device__ __forceinline__ uint4 cvt8(float4 a, float4 b) {
    uint4 r;
    r.x = pack2bf(a.x, a.y); r.y = pack2bf(a.z, a.w);
    r.z = pack2bf(b.x, b.y); r.w = pack2bf(b.z, b.w);
    return r;
}

// ---------------------------------------------------------------------------
// Pack all weights (f32 row-major [K][N]) into bf16 MFMA B-fragment order:
// frag index = (ct*KB + kb)*64 + lane ; lane holds W[kb*32+(lane>>4)*8+j][ct*16+(lane&15)]
// mode 1: eq0_W1 remap into padded 448-row layout (rows 32..191 zero).
// ---------------------------------------------------------------------------
__global__ void pack_all(const float* __restrict__ eq0W1, const float* __restrict__ eq1W1,
                         const float* __restrict__ invW1, const float* __restrict__ eq0W2,
                         const float* __restrict__ eq1W2, const float* __restrict__ invW2,
                         const float* __restrict__ Wrbf,  ushort_t* __restrict__ out)
{
    const int tid = blockIdx.x * blockDim.x + threadIdx.x;
    if (tid >= PK_TOTAL) return;
    int base, KB, N, mode = 0;
    const float* src;
    if      (tid < PK_W1EQ1)  { base = PK_W1EQ0;  KB = 14; N = 128; src = eq0W1; mode = 1; }
    else if (tid < PK_W1INV0) { base = PK_W1EQ1;  KB = 14; N = 128; src = eq1W1; }
    else if (tid < PK_W1INV1) { base = PK_W1INV0; KB = 14; N = 128; src = invW1; }
    else if (tid < PK_W2EQ0)  { base = PK_W1INV1; KB = 14; N = 128; src = invW1 + 448 * 128; }
    else if (tid < PK_W2EQ1)  { base = PK_W2EQ0;  KB = 4;  N = 64;  src = eq0W2; }
    else if (tid < PK_W2INV0) { base = PK_W2EQ1;  KB = 4;  N = 64;  src = eq1W2; }
    else if (tid < PK_W2INV1) { base = PK_W2INV0; KB = 4;  N = 128; src = invW2; }
    else if (tid < PK_WRBF)   { base = PK_W2INV1; KB = 4;  N = 128; src = invW2 + 128 * 128; }
    else                      { base = PK_WRBF;   KB = 10; N = 32;  src = Wrbf; }
    const int local = tid - base;
    const int lane  = local & 63;
    const int rest  = local >> 6;
    const int kb    = rest % KB;
    const int ct    = rest / KB;
    const int col   = ct * 16 + (lane & 15);
    const int k0    = kb * 32 + ((lane >> 4) * 8);
    ushort_t v[8];
    #pragma unroll
    for (int j = 0; j < 8; j++) {
        const int k = k0 + j;
        float x;
        if (mode == 1) x = (k < 32) ? src[k * N + col] : (k < 192 ? 0.f : src[(k - 160) * N + col]);
        else           x = src[(size_t)k * N + col];
        v[j] = f2bf(x);
    }
    *(uint4*)(out + (size_t)tid * 8) = *(uint4*)v;
}

// ---------------------------------------------------------------------------
// Fused MFMA edge kernel. 64 edges/block, 512 threads (8 waves).
// ---------------------------------------------------------------------------
__global__ __launch_bounds__(512, 2)
void edge_kernel(const float* __restrict__ rbfs,
                 const float* __restrict__ dists,
                 const float* __restrict__ vecs,
                 const float* __restrict__ cuts,
                 const int*   __restrict__ gidx_i,
                 const int*   __restrict__ gidx_j,
                 const float* __restrict__ s_in,
                 const float* __restrict__ v_in,
                 const ushort_t* __restrict__ pWrbf,
                 const ushort_t* __restrict__ pW1eq,
                 const float* __restrict__ b1eq,
                 const ushort_t* __restrict__ pW2eq,
                 const ushort_t* __restrict__ pW1inv,
                 const float* __restrict__ b1inv,
                 const ushort_t* __restrict__ pW2inv,
                 const float* __restrict__ b2inv,
                 float* __restrict__ s_out,
                 float* __restrict__ v_out,
                 const int eqSkip)
{
    __shared__ __align__(16) char smem[SMEM_SZ];
    ushort_t* xs  = (ushort_t*)(smem + XS_OFF);
    ushort_t* hbA = (ushort_t*)(smem + HBA_OFF);
    ushort_t* hbB = (ushort_t*)(smem + HBB_OFF);
    float*    us  = (float*)(smem + US_OFF);
    int*      iis = (int*)(smem + IIS_OFF);
    int*      jjs = (int*)(smem + JJS_OFF);
    float*    ml  = (float*)(smem + ML_OFF);
    float*    gl  = (float*)(smem + GL_OFF);

    const int t    = threadIdx.x;
    const int p0   = blockIdx.x * ET;
    const int lane = t & 63;
    const int wid  = t >> 6;
    const int colf = lane & 15;
    const int krow = (lane >> 4) * 8;

    // ---------------- stage: si/sj/rbf -> xs (bf16), us, iis, jjs -------------
    {
        const int e = t >> 3, l = t & 7;
        const int p = p0 + e;
        const int i = gidx_i[p];
        const int j = gidx_j[p];
        const float4* si4 = (const float4*)(s_in + (size_t)i * FDIM);
        const float4* sj4 = (const float4*)(s_in + (size_t)j * FDIM);
        float4 a0 = si4[l * 4 + 0], a1 = si4[l * 4 + 1], a2 = si4[l * 4 + 2], a3 = si4[l * 4 + 3];
        *(uint4*)&xs[e * XSTR + 192 + l * 16]     = cvt8(a0, a1);
        *(uint4*)&xs[e * XSTR + 192 + l * 16 + 8] = cvt8(a2, a3);
        float4 b0 = sj4[l * 4 + 0], b1 = sj4[l * 4 + 1], b2 = sj4[l * 4 + 2], b3 = sj4[l * 4 + 3];
        *(uint4*)&xs[e * XSTR + 320 + l * 16]     = cvt8(b0, b1);
        *(uint4*)&xs[e * XSTR + 320 + l * 16 + 8] = cvt8(b2, b3);
        const float4* rb4 = (const float4*)(rbfs + (size_t)p * 64);
        float4 r0 = rb4[l * 2], r1 = rb4[l * 2 + 1];
        *(uint4*)&xs[e * XSTR + 448 + l * 8] = cvt8(r0, r1);
        if (t < ET) {
            const int pp = p0 + t;
            const float dinv = 1.0f / (dists[pp] + 0.001f);
            float4 uu;
            uu.x = vecs[pp * 3 + 0] * dinv;
            uu.y = vecs[pp * 3 + 1] * dinv;
            uu.z = vecs[pp * 3 + 2] * dinv;
            uu.w = cuts[pp];
            *(float4*)&us[t * 4] = uu;
            jjs[t] = gidx_j[pp];
        }
        if (t < ET + 1) {
            const int pp = p0 + t;
            iis[t] = (pp < PE) ? gidx_i[pp] : -1;
        }
    }
    __syncthreads();

    // ---------------- a_* terms -> xs cols [32,192) (bf16) --------------------
    {
        const int e  = t >> 3;
        const int m0 = (t & 7) * 4;
        const int i = iis[e];
        const int j = jjs[e];
        float vi[3][4], vj[3][4];
        #pragma unroll
        for (int d = 0; d < 3; d++) {
            const float4 a = *(const float4*)(v_in + (size_t)i * 96 + d * 32 + m0);
            const float4 b = *(const float4*)(v_in + (size_t)j * 96 + d * 32 + m0);
            vi[d][0] = a.x; vi[d][1] = a.y; vi[d][2] = a.z; vi[d][3] = a.w;
            vj[d][0] = b.x; vj[d][1] = b.y; vj[d][2] = b.z; vj[d][3] = b.w;
        }
        const float ux = us[e * 4 + 0], uy = us[e * 4 + 1], uz = us[e * 4 + 2];
        float aui[4], auj[4], aij[4], aii[4], ajj[4];
        #pragma unroll
        for (int mm = 0; mm < 4; mm++) {
            aui[mm] = ux * vi[0][mm] + uy * vi[1][mm] + uz * vi[2][mm];
            auj[mm] = ux * vj[0][mm] + uy * vj[1][mm] + uz * vj[2][mm];
            aij[mm] = vi[0][mm] * vj[0][mm] + vi[1][mm] * vj[1][mm] + vi[2][mm] * vj[2][mm];
            aii[mm] = vi[0][mm] * vi[0][mm] + vi[1][mm] * vi[1][mm] + vi[2][mm] * vi[2][mm];
            ajj[mm] = vj[0][mm] * vj[0][mm] + vj[1][mm] * vj[1][mm] + vj[2][mm] * vj[2][mm];
        }
        uint2 w;
        w.x = pack2bf(aui[0], aui[1]); w.y = pack2bf(aui[2], aui[3]);
        *(uint2*)&xs[e * XSTR + 32 + m0] = w;
        w.x = pack2bf(auj[0], auj[1]); w.y = pack2bf(auj[2], auj[3]);
        *(uint2*)&xs[e * XSTR + 64 + m0] = w;
        w.x = pack2bf(aij[0], aij[1]); w.y = pack2bf(aij[2], aij[3]);
        *(uint2*)&xs[e * XSTR + 96 + m0] = w;
        w.x = pack2bf(aii[0], aii[1]); w.y = pack2bf(aii[2], aii[3]);
        *(uint2*)&xs[e * XSTR + 128 + m0] = w;
        w.x = pack2bf(ajj[0], ajj[1]); w.y = pack2bf(ajj[2], ajj[3]);
        *(uint2*)&xs[e * XSTR + 160 + m0] = w;
    }

    // ---------------- e = [rbf|si|sj] @ Wrbf via MFMA -> regs -----------------
    f32x4 eacc = {0.f, 0.f, 0.f, 0.f};
    {
        const int rt = wid & 3;       // row-tile
        const int ct = wid >> 2;      // col-tile (0..1)
        #pragma unroll
        for (int kb = 0; kb < 10; kb++) {
            bf16x8 bf = *(const bf16x8*)(pWrbf + ((size_t)(ct * 10 + kb) * 64 + lane) * 8);
            const int xcol = (kb < 2) ? (448 + kb * 32 + krow) : (128 + kb * 32 + krow);
            bf16x8 af = *(const bf16x8*)&xs[(rt * 16 + colf) * XSTR + xcol];
            eacc = MFMA16(af, bf, eacc, 0, 0, 0);
        }
        __syncthreads();   // a_* writes + all Wrbf A-reads done
        #pragma unroll
        for (int r = 0; r < 4; r++) {
            const int row = rt * 16 + (lane >> 4) * 4 + r;
            xs[row * XSTR + ct * 16 + colf] = f2bf(eacc[r]);
        }
    }
    __syncthreads();   // x tile complete

    // ---------------- GEMM1-eq: h1_eq = silu(x @ W1eq + b1eq) -----------------
    {
        f32x4 acc[4];
        const float bc = b1eq[wid * 16 + colf];
        #pragma unroll
        for (int rt = 0; rt < 4; rt++) acc[rt] = (f32x4){bc, bc, bc, bc};
        #pragma unroll
        for (int kb = 0; kb < 14; kb++) {
            if (eqSkip && kb >= 1 && kb < 6) continue;
            bf16x8 bf = *(const bf16x8*)(pW1eq + ((size_t)(wid * 14 + kb) * 64 + lane) * 8);
            #pragma unroll
            for (int rt = 0; rt < 4; rt++) {
                bf16x8 af = *(const bf16x8*)&xs[(rt * 16 + colf) * XSTR + kb * 32 + krow];
                acc[rt] = MFMA16(af, bf, acc[rt], 0, 0, 0);
            }
        }
        #pragma unroll
        for (int rt = 0; rt < 4; rt++)
            #pragma unroll
            for (int r = 0; r < 4; r++) {
                const int row = rt * 16 + (lane >> 4) * 4 + r;
                hbA[row * HSTR + wid * 16 + colf] = f2bf(silu_f(acc[rt][r]));
            }
    }
    // ---------------- GEMM1-inv: h1_inv = silu(x @ W1inv + b1inv) -------------
    {
        f32x4 acc[4];
        const float bc = b1inv[wid * 16 + colf];
        #pragma unroll
        for (int rt = 0; rt < 4; rt++) acc[rt] = (f32x4){bc, bc, bc, bc};
        #pragma unroll
        for (int kb = 0; kb < 14; kb++) {
            bf16x8 bf = *(const bf16x8*)(pW1inv + ((size_t)(wid * 14 + kb) * 64 + lane) * 8);
            #pragma unroll
            for (int rt = 0; rt < 4; rt++) {
                bf16x8 af = *(const bf16x8*)&xs[(rt * 16 + colf) * XSTR + kb * 32 + krow];
                acc[rt] = MFMA16(af, bf, acc[rt], 0, 0, 0);
            }
        }
        #pragma unroll
        for (int rt = 0; rt < 4; rt++)
            #pragma unroll
            for (int r = 0; r < 4; r++) {
                const int row = rt * 16 + (lane >> 4) * 4 + r;
                hbB[row * HSTR + wid * 16 + colf] = f2bf(silu_f(acc[rt][r]));
            }
    }
    __syncthreads();   // h1 tiles ready; xs free for aliasing

    // ---------------- GEMM2-eq (g) + GEMM2-inv (m) ----------------------------
    f32x4 gacc[2];
    {
        const int ct2 = wid & 3;
        const int rh  = wid >> 2;
        gacc[0] = (f32x4){0.f, 0.f, 0.f, 0.f};
        gacc[1] = (f32x4){0.f, 0.f, 0.f, 0.f};
        #pragma unroll
        for (int kb = 0; kb < 4; kb++) {
            bf16x8 bf = *(const bf16x8*)(pW2eq + ((size_t)(ct2 * 4 + kb) * 64 + lane) * 8);
            #pragma unroll
            for (int q = 0; q < 2; q++) {
                bf16x8 af = *(const bf16x8*)&hbA[((rh * 2 + q) * 16 + colf) * HSTR + kb * 32 + krow];
                gacc[q] = MFMA16(af, bf, gacc[q], 0, 0, 0);
            }
        }
    }
    f32x4 macc[4];
    {
        const float bc = b2inv[wid * 16 + colf];
        #pragma unroll
        for (int rt = 0; rt < 4; rt++) macc[rt] = (f32x4){bc, bc, bc, bc};
        #pragma unroll
        for (int kb = 0; kb < 4; kb++) {
            bf16x8 bf = *(const bf16x8*)(pW2inv + ((size_t)(wid * 4 + kb) * 64 + lane) * 8);
            #pragma unroll
            for (int rt = 0; rt < 4; rt++) {
                bf16x8 af = *(const bf16x8*)&hbB[(rt * 16 + colf) * HSTR + kb * 32 + krow];
                macc[rt] = MFMA16(af, bf, macc[rt], 0, 0, 0);
            }
        }
    }
    // write g (f32, xs alias) and m = silu(.)*cut (f32, xs alias)
    {
        const int ct2 = wid & 3;
        const int rh  = wid >> 2;
        #pragma unroll
        for (int q = 0; q < 2; q++)
            #pragma unroll
            for (int r = 0; r < 4; r++) {
                const int row = (rh * 2 + q) * 16 + (lane >> 4) * 4 + r;
                gl[row * 68 + ct2 * 16 + colf] = gacc[q][r];
            }
        #pragma unroll
        for (int rt = 0; rt < 4; rt++)
            #pragma unroll
            for (int r = 0; r < 4; r++) {
                const int row = rt * 16 + (lane >> 4) * 4 + r;
                ml[row * 132 + wid * 16 + colf] = silu_f(macc[rt][r]) * us[row * 4 + 3];
            }
    }
    __syncthreads();

    // ---------------- sorted-run scan + scatter (two 32-edge halves) ----------
    {
        const int half = t >> 8;          // 0 or 1
        const int tl   = t & 255;
        if (tl < 224) {
            const int e0 = half * 32;
            if (tl < FDIM) {
                float acc = 0.f;
                for (int e = e0; e < e0 + 32; e++) {
                    acc += ml[e * 132 + tl];
                    if (e == e0 + 31 || iis[e + 1] != iis[e]) {
                        atomicAdd(&s_out[(size_t)iis[e] * FDIM + tl], acc);
                        acc = 0.f;
                    }
                }
            } else {
                const int col = tl - FDIM;          // 0..95
                const int d   = col >> 5;
                const int mm  = col & 31;
                float acc = 0.f;
                for (int e = e0; e < e0 + 32; e++) {
                    const float g0  = gl[e * 68 + mm];
                    const float g1  = gl[e * 68 + 32 + mm];
                    const float vjv = v_in[(size_t)jjs[e] * 96 + col];
                    acc = fmaf(us[e * 4 + 3], fmaf(g0, us[e * 4 + d], g1 * vjv), acc);
                    if (e == e0 + 31 || iis[e + 1] != iis[e]) {
                        atomicAdd(&v_out[(size_t)iis[e] * 96 + col], acc);
                        acc = 0.f;
                    }
                }
            }
        }
    }
}

// ---------------------------------------------------------------------------
// Node update (fp32, verified): s += silu(silu([s, s@Wemb] @ W1u + b1u) @ W2u + b2u)
// ---------------------------------------------------------------------------
__device__ __forceinline__ void fma_4k(float (&acc)[4], const float4 xv,
                                       const float4 w0, const float4 w1,
                                       const float4 w2, const float4 w3) {
    acc[0] = fmaf(xv.x, w0.x, fmaf(xv.y, w1.x, fmaf(xv.z, w2.x, fmaf(xv.w, w3.x, acc[0]))));
    acc[1] = fmaf(xv.x, w0.y, fmaf(xv.y, w1.y, fmaf(xv.z, w2.y, fmaf(xv.w, w3.y, acc[1]))));
    acc[2] = fmaf(xv.x, w0.z, fmaf(xv.y, w1.z, fmaf(xv.z, w2.z, fmaf(xv.w, w3.z, acc[2]))));
    acc[3] = fmaf(xv.x, w0.w, fmaf(xv.y, w1.w, fmaf(xv.z, w2.w, fmaf(xv.w, w3.w, acc[3]))));
}

__global__ __launch_bounds__(256, 2)
void node_kernel(const float* __restrict__ s_in,
                 const float* __restrict__ Wemb,
                 const float* __restrict__ W1u,
                 const float* __restrict__ b1u,
                 const float* __restrict__ W2u,
                 const float* __restrict__ b2u,
                 float* __restrict__ s_out)
{
    __shared__ float ss[AT][HS];
    __shared__ float fe[AT][HS];
    __shared__ float t1[AT][HS];
    const int t  = threadIdx.x;
    const int a0 = blockIdx.x * AT;

    {
        const int a = t >> 3, l = t & 7;
        const float4* sr = (const float4*)(s_in + (size_t)(a0 + a) * FDIM);
        #pragma unroll
        for (int q = 0; q < 4; q++) {
            const int c4 = l + 8 * q;
            *(float4*)&ss[a][4 * c4] = sr[c4];
        }
    }
    __syncthreads();

    const int e0 = (t >> 5) * 4;
    const int c0 = (t & 31) * 4;

    {
        float acc[4][4];
        #pragma unroll
        for (int ee = 0; ee < 4; ee++) {
            acc[ee][0] = 0.f; acc[ee][1] = 0.f; acc[ee][2] = 0.f; acc[ee][3] = 0.f;
        }
        for (int k = 0; k < FDIM; k += 4) {
            const float4 w0 = *(const float4*)(Wemb + (size_t)(k + 0) * FDIM + c0);
            const float4 w1 = *(const float4*)(Wemb + (size_t)(k + 1) * FDIM + c0);
            const float4 w2 = *(const float4*)(Wemb + (size_t)(k + 2) * FDIM + c0);
            const float4 w3 = *(const float4*)(Wemb + (size_t)(k + 3) * FDIM + c0);
            #pragma unroll
            for (int ee = 0; ee < 4; ee++) {
                const float4 xv = *(const float4*)&ss[e0 + ee][k];
                fma_4k(acc[ee], xv, w0, w1, w2, w3);
            }
        }
        #pragma unroll
        for (int ee = 0; ee < 4; ee++)
            *(float4*)&fe[e0 + ee][c0] =
                make_float4(acc[ee][0], acc[ee][1], acc[ee][2], acc[ee][3]);
    }
    __syncthreads();

    {
        float acc[4][4];
        const float4 b = *(const float4*)(b1u + c0);
        #pragma unroll
        for (int ee = 0; ee < 4; ee++) {
            acc[ee][0] = b.x; acc[ee][1] = b.y; acc[ee][2] = b.z; acc[ee][3] = b.w;
        }
        for (int k = 0; k < FDIM; k += 4) {
            const float4 w0 = *(const float4*)(W1u + (size_t)(k + 0) * FDIM + c0);
            const float4 w1 = *(const float4*)(W1u + (size_t)(k + 1) * FDIM + c0);
            const float4 w2 = *(const float4*)(W1u + (size_t)(k + 2) * FDIM + c0);
            const float4 w3 = *(const float4*)(W1u + (size_t)(k + 3) * FDIM + c0);
            #pragma unroll
            for (int ee = 0; ee < 4; ee++) {
                const float4 xv = *(const float4*)&ss[e0 + ee][k];
                fma_4k(acc[ee], xv, w0, w1, w2, w3);
            }
        }
        for (int k = 0; k < FDIM; k += 4) {
            const float4 w0 = *(const float4*)(W1u + (size_t)(FDIM + k + 0) * FDIM + c0);
            const float4 w1 = *(const float4*)(W1u + (size_t)(FDIM + k + 1) * FDIM + c0);
            const float4 w2 = *(const float4*)(W1u + (size_t)(FDIM + k + 2) * FDIM + c0);
            const float4 w3 = *(const float4*)(W1u + (size_t)(FDIM + k + 3) * FDIM + c0);
            #pragma unroll
            for (int ee = 0; ee < 4; ee++) {
                const float4 xv = *(const float4*)&fe[e0 + ee][k];
                fma_4k(acc[ee], xv, w0, w1, w2, w3);
            }
        }
        #pragma unroll
        for (int ee = 0; ee < 4; ee++) {
            float4 o;
            o.x = silu_f(acc[ee][0]); o.y = silu_f(acc[ee][1]);
            o.z = silu_f(acc[ee][2]); o.w = silu_f(acc[ee][3]);
            *(float4*)&t1[e0 + ee][c0] = o;
        }
    }
    __syncthreads();

    {
        float acc[4][4];
        const float4 b = *(const float4*)(b2u + c0);
        #pragma unroll
        for (int ee = 0; ee < 4; ee++) {
            acc[ee][0] = b.x; acc[ee][1] = b.y; acc[ee][2] = b.z; acc[ee][3] = b.w;
        }
        for (int k = 0; k < FDIM; k += 4) {
            const float4 w0 = *(const float4*)(W2u + (size_t)(k + 0) * FDIM + c0);
            const float4 w1 = *(const float4*)(W2u + (size_t)(k + 1) * FDIM + c0);
            const float4 w2 = *(const float4*)(W2u + (size_t)(k + 2) * FDIM + c0);
            const float4 w3 = *(const float4*)(W2u + (size_t)(k + 3) * FDIM + c0);
            #pragma unroll
            for (int ee = 0; ee < 4; ee++) {
                const float4 xv = *(const float4*)&t1[e0 + ee][k];
                fma_4k(acc[ee], xv, w0, w1, w2, w3);
            }
        }
        #pragma unroll
        for (int ee = 0; ee < 4; ee++) {
            float4 o;
            o.x = ss[e0 + ee][c0 + 0] + silu_f(acc[ee][0]);
            o.y = ss[e0 + ee][c0 + 1] + silu_f(acc[ee][1]);
            o.z = ss[e0 + ee][c0 + 2] + silu_f(acc[ee][2]);
            o.w = ss[e0 + ee][c0 + 3] + silu_f(acc[ee][3]);
            *(float4*)(s_out + (size_t)(a0 + e0 + ee) * FDIM + c0) = o;
        }
    }
}

// ---------------------------------------------------------------------------
__global__ void copyf4(float4* __restrict__ dst, const float4* __restrict__ src, int n4) {
    int i = blockIdx.x * blockDim.x + threadIdx.x;
    const int stride = gridDim.x * blockDim.x;
    for (; i < n4; i += stride) dst[i] = src[i];
}

__global__ void zerof4(float4* __restrict__ dst, int n4) {
    int i = blockIdx.x * blockDim.x + threadIdx.x;
    const int stride = gridDim.x * blockDim.x;
    const float4 z = make_float4(0.f, 0.f, 0.f, 0.f);
    for (; i < n4; i += stride) dst[i] = z;
}

// ---------------------------------------------------------------------------
extern "C" void kernel_launch(void* const* d_in, const int* in_sizes, int n_in,
                              void* d_out, int out_size, void* d_ws, size_t ws_size,
                              hipStream_t stream) {
    (void)in_sizes; (void)n_in; (void)out_size; (void)ws_size;

    const float* features = (const float*)d_in[0];
    const float* dists    = (const float*)d_in[1];
    const float* vecs     = (const float*)d_in[2];
    const float* cuts     = (const float*)d_in[3];
    const float* rbfs     = (const float*)d_in[4];
    const int*   idx_i    = (const int*)d_in[5];
    const int*   idx_j    = (const int*)d_in[6];
    const float* Wrbf     = (const float*)d_in[7];
    const float* Wemb     = (const float*)d_in[8];
    const float* eq0_W1   = (const float*)d_in[9];
    const float* eq0_b1   = (const float*)d_in[10];
    const float* eq0_W2   = (const float*)d_in[11];
    const float* eq1_W1   = (const float*)d_in[12];
    const float* eq1_b1   = (const float*)d_in[13];
    const float* eq1_W2   = (const float*)d_in[14];
    const float* inv_W1   = (const float*)d_in[15];
    const float* inv_b1   = (const float*)d_in[16];
    const float* inv_W2   = (const float*)d_in[17];
    const float* inv_b2   = (const float*)d_in[18];
    const float* upd_W1   = (const float*)d_in[19];
    const float* upd_b1   = (const float*)d_in[20];
    const float* upd_W2   = (const float*)d_in[21];
    const float* upd_b2   = (const float*)d_in[22];

    float* sA = (float*)d_ws;
    float* sB = sA + (size_t)NA * FDIM;
    float* vA = sB + (size_t)NA * FDIM;
    float* vB = vA + (size_t)NA * 96;
    ushort_t* pwb = (ushort_t*)(vB + (size_t)NA * 96);

    float* s_final = (float*)d_out;
    float* v_final = s_final + (size_t)NA * FDIM;

    const int SN4 = NA * FDIM / 4;
    const int VN4 = NA * 96 / 4;

    pack_all<<<(PK_TOTAL + 255) / 256, 256, 0, stream>>>(
        eq0_W1, eq1_W1, inv_W1, eq0_W2, eq1_W2, inv_W2, Wrbf, pwb);
    copyf4<<<1024, 256, 0, stream>>>((float4*)sA, (const float4*)features, SN4);
    copyf4<<<1024, 256, 0, stream>>>((float4*)sB, (const float4*)features, SN4);
    zerof4<<<1024, 256, 0, stream>>>((float4*)vA, VN4);
    zerof4<<<1024, 256, 0, stream>>>((float4*)vB, VN4);

    // ---- block 0: read (sA, vA) -> accum (sB, vB); node: sB -> sA ----
    edge_kernel<<<PE / ET, 512, 0, stream>>>(
        rbfs, dists, vecs, cuts, idx_i, idx_j, sA, vA,
        pwb + (size_t)PK_WRBF * 8,
        pwb + (size_t)PK_W1EQ0 * 8, eq0_b1, pwb + (size_t)PK_W2EQ0 * 8,
        pwb + (size_t)PK_W1INV0 * 8, inv_b1, pwb + (size_t)PK_W2INV0 * 8, inv_b2,
        sB, vB, 1);
    node_kernel<<<NA / AT, 256, 0, stream>>>(sB, Wemb, upd_W1, upd_b1, upd_W2, upd_b2, sA);

    // ---- block 1: read (sA, vB) -> accum (sB, vA); node: sB -> d_out ----
    copyf4<<<1024, 256, 0, stream>>>((float4*)sB, (const float4*)sA, SN4);
    copyf4<<<1024, 256, 0, stream>>>((float4*)vA, (const float4*)vB, VN4);
    edge_kernel<<<PE / ET, 512, 0, stream>>>(
        rbfs, dists, vecs, cuts, idx_i, idx_j, sA, vB,
        pwb + (size_t)PK_WRBF * 8,
        pwb + (size_t)PK_W1EQ1 * 8, eq1_b1, pwb + (size_t)PK_W2EQ1 * 8,
        pwb + (size_t)PK_W1INV1 * 8, inv_b1 + FDIM, pwb + (size_t)PK_W2INV1 * 8, inv_b2 + FDIM,
        sB, vA, 0);
    node_kernel<<<NA / AT, 256, 0, stream>>>(
        sB, Wemb, upd_W1 + 2 * FDIM * FDIM, upd_b1 + FDIM,
        upd_W2 + FDIM * FDIM, upd_b2 + FDIM, s_final);

    copyf4<<<1024, 256, 0, stream>>>((float4*)v_final, (const float4*)vA, VN4);
}

// Round 3
// 653.855 us; speedup vs baseline: 5.8834x; 1.5781x over previous
//
#include <hip/hip_runtime.h>
#include <math.h>

#define NA   20000
#define PE   320000
#define FDIM 128
#define ET   64          // edges per block (edge kernel)
#define AT   32          // atoms per block (node kernel)

typedef unsigned short ushort_t;
typedef __attribute__((ext_vector_type(8))) short bf16x8;
typedef __attribute__((ext_vector_type(4))) float f32x4;
#define MFMA16 __builtin_amdgcn_mfma_f32_16x16x32_bf16

// ---------------- edge kernel LDS map (bytes) ----------------
#define XSTR     456        // ushort stride; 228 words, %32==4 -> conflict-free b128
#define HSTR     136        // ushort stride; 68 words, %32==4
#define XS_OFF   0          // ushort [64][456]  x tile (cols 0..447)
#define H1_OFF   58368      // ushort [64][136]  rbf (stage) -> h1_eq -> h1_inv
#define US_OFF   75776      // float  [64][4]    ux,uy,uz,cut
#define IIS_OFF  76800      // int [65]
#define JJS_OFF  77064      // int [64]
#define SMEM_SZ  77320
// f32 aliases over xs (dead after fused GEMM1)
#define ML_OFF   0          // float [64][132]  m
#define GL_OFF   33792      // float [64][68]   g

// ---------------- packed-weight fragment bases (1 frag = 8 ushort = 16B) ----
#define PK_W1EQ0   0        // 14kb x 8ct x 64
#define PK_W1EQ1   7168
#define PK_W1INV0  14336
#define PK_W1INV1  21504
#define PK_W2EQ0   28672    // 4kb x 4ct x 64
#define PK_W2EQ1   29696
#define PK_W2INV0  30720    // 4kb x 8ct x 64
#define PK_W2INV1  32768
#define PK_WRBF    34816    // 10kb x 2ct x 64
#define PK_WEMB    36096    // 4kb x 8ct x 64
#define PK_W1U0    38144    // 8kb x 8ct x 64
#define PK_W1U1    42240
#define PK_W2U0    46336    // 4kb x 8ct x 64
#define PK_W2U1    48384
#define PK_TOTAL   50432

__device__ __forceinline__ float silu_f(float z) {
    return z / (1.0f + __expf(-z));
}

// native bf16 cast -> compiler emits v_cvt_pk_bf16_f32 for pairs
__device__ __forceinline__ ushort_t f2bf(float x) {
    __bf16 h = (__bf16)x;
    union { __bf16 b; ushort_t u; } c; c.b = h; return c.u;
}

__device__ __forceinline__ unsigned int pack2bf(float x, float y) {
    return (unsigned int)f2bf(x) | ((unsigned int)f2bf(y) << 16);
}

__device__ __forceinline__ uint4 cvt8(float4 a, float4 b) {
    uint4 r;
    r.x = pack2bf(a.x, a.y); r.y = pack2bf(a.z, a.w);
    r.z = pack2bf(b.x, b.y); r.w = pack2bf(b.z, b.w);
    return r;
}

// ---------------------------------------------------------------------------
// Pack all weights (f32 row-major [K][N]) into bf16 MFMA B-fragment order:
// frag (ct*KB + kb)*64 + lane : lane holds W[kb*32+(lane>>4)*8+j][ct*16+(lane&15)]
// mode 1: eq0_W1 remap into padded 448-row layout (rows 32..191 zero).
// ---------------------------------------------------------------------------
__global__ void pack_all(const float* __restrict__ eq0W1, const float* __restrict__ eq1W1,
                         const float* __restrict__ invW1, const float* __restrict__ eq0W2,
                         const float* __restrict__ eq1W2, const float* __restrict__ invW2,
                         const float* __restrict__ Wrbf,  const float* __restrict__ Wemb,
                         const float* __restrict__ updW1, const float* __restrict__ updW2,
                         ushort_t* __restrict__ out)
{
    const int tid = blockIdx.x * blockDim.x + threadIdx.x;
    if (tid >= PK_TOTAL) return;
    int base, KB, N, mode = 0;
    const float* src;
    if      (tid < PK_W1EQ1)  { base = PK_W1EQ0;  KB = 14; N = 128; src = eq0W1; mode = 1; }
    else if (tid < PK_W1INV0) { base = PK_W1EQ1;  KB = 14; N = 128; src = eq1W1; }
    else if (tid < PK_W1INV1) { base = PK_W1INV0; KB = 14; N = 128; src = invW1; }
    else if (tid < PK_W2EQ0)  { base = PK_W1INV1; KB = 14; N = 128; src = invW1 + 448 * 128; }
    else if (tid < PK_W2EQ1)  { base = PK_W2EQ0;  KB = 4;  N = 64;  src = eq0W2; }
    else if (tid < PK_W2INV0) { base = PK_W2EQ1;  KB = 4;  N = 64;  src = eq1W2; }
    else if (tid < PK_W2INV1) { base = PK_W2INV0; KB = 4;  N = 128; src = invW2; }
    else if (tid < PK_WRBF)   { base = PK_W2INV1; KB = 4;  N = 128; src = invW2 + 128 * 128; }
    else if (tid < PK_WEMB)   { base = PK_WRBF;   KB = 10; N = 32;  src = Wrbf; }
    else if (tid < PK_W1U0)   { base = PK_WEMB;   KB = 4;  N = 128; src = Wemb; }
    else if (tid < PK_W1U1)   { base = PK_W1U0;   KB = 8;  N = 128; src = updW1; }
    else if (tid < PK_W2U0)   { base = PK_W1U1;   KB = 8;  N = 128; src = updW1 + 256 * 128; }
    else if (tid < PK_W2U1)   { base = PK_W2U0;   KB = 4;  N = 128; src = updW2; }
    else                      { base = PK_W2U1;   KB = 4;  N = 128; src = updW2 + 128 * 128; }
    const int local = tid - base;
    const int lane  = local & 63;
    const int rest  = local >> 6;
    const int kb    = rest % KB;
    const int ct    = rest / KB;
    const int col   = ct * 16 + (lane & 15);
    const int k0    = kb * 32 + ((lane >> 4) * 8);
    ushort_t v[8];
    #pragma unroll
    for (int j = 0; j < 8; j++) {
        const int k = k0 + j;
        float x;
        if (mode == 1) x = (k < 32) ? src[k * N + col] : (k < 192 ? 0.f : src[(k - 160) * N + col]);
        else           x = src[(size_t)k * N + col];
        v[j] = f2bf(x);
    }
    *(uint4*)(out + (size_t)tid * 8) = *(uint4*)v;
}

// ---------------------------------------------------------------------------
// Fused MFMA edge kernel. 64 edges/block, 512 threads (8 waves), 2 blocks/CU.
// ---------------------------------------------------------------------------
__global__ __launch_bounds__(512, 4)
void edge_kernel(const float* __restrict__ rbfs,
                 const float* __restrict__ dists,
                 const float* __restrict__ vecs,
                 const float* __restrict__ cuts,
                 const int*   __restrict__ gidx_i,
                 const int*   __restrict__ gidx_j,
                 const ushort_t* __restrict__ s_bf,    // bf16 mirror of s
                 const float* __restrict__ v_in,
                 const ushort_t* __restrict__ pWrbf,
                 const ushort_t* __restrict__ pW1eq,
                 const float* __restrict__ b1eq,
                 const ushort_t* __restrict__ pW2eq,
                 const ushort_t* __restrict__ pW1inv,
                 const float* __restrict__ b1inv,
                 const ushort_t* __restrict__ pW2inv,
                 const float* __restrict__ b2inv,
                 float* __restrict__ s_out,
                 float* __restrict__ v_out,
                 const int eqSkip)
{
    __shared__ __align__(16) char smem[SMEM_SZ];
    ushort_t* xs  = (ushort_t*)(smem + XS_OFF);
    ushort_t* h1  = (ushort_t*)(smem + H1_OFF);
    float*    us  = (float*)(smem + US_OFF);
    int*      iis = (int*)(smem + IIS_OFF);
    int*      jjs = (int*)(smem + JJS_OFF);
    float*    ml  = (float*)(smem + ML_OFF);
    float*    gl  = (float*)(smem + GL_OFF);

    const int t    = threadIdx.x;
    const int p0   = blockIdx.x * ET;
    const int lane = t & 63;
    const int wid  = t >> 6;
    const int colf = lane & 15;
    const int krow = (lane >> 4) * 8;

    // ---------------- stage: si/sj (bf16 direct), rbf (f32->bf16), us/iis/jjs --
    {
        const int e = t >> 3, l = t & 7;
        const int p = p0 + e;
        const int i = gidx_i[p];
        const int j = gidx_j[p];
        const uint4* si4 = (const uint4*)(s_bf + (size_t)i * FDIM);
        const uint4* sj4 = (const uint4*)(s_bf + (size_t)j * FDIM);
        *(uint4*)&xs[e * XSTR + 192 + l * 16]     = si4[l * 2];
        *(uint4*)&xs[e * XSTR + 192 + l * 16 + 8] = si4[l * 2 + 1];
        *(uint4*)&xs[e * XSTR + 320 + l * 16]     = sj4[l * 2];
        *(uint4*)&xs[e * XSTR + 320 + l * 16 + 8] = sj4[l * 2 + 1];
        const float4* rb4 = (const float4*)(rbfs + (size_t)p * 64);
        float4 r0 = rb4[l * 2], r1 = rb4[l * 2 + 1];
        *(uint4*)&h1[e * HSTR + l * 8] = cvt8(r0, r1);   // rbf staged in h1 region
        if (t < ET) {
            const int pp = p0 + t;
            const float dinv = 1.0f / (dists[pp] + 0.001f);
            float4 uu;
            uu.x = vecs[pp * 3 + 0] * dinv;
            uu.y = vecs[pp * 3 + 1] * dinv;
            uu.z = vecs[pp * 3 + 2] * dinv;
            uu.w = cuts[pp];
            *(float4*)&us[t * 4] = uu;
            jjs[t] = gidx_j[pp];
        }
        if (t < ET + 1) {
            const int pp = p0 + t;
            iis[t] = (pp < PE) ? gidx_i[pp] : -1;
        }
    }
    __syncthreads();   // (1)

    // ---------------- a_* terms -> xs cols [32,192) (f32 math, bf16 pack) -----
    {
        const int e  = t >> 3;
        const int m0 = (t & 7) * 4;
        const int i = iis[e];
        const int j = jjs[e];
        float vi[3][4], vj[3][4];
        #pragma unroll
        for (int d = 0; d < 3; d++) {
            const float4 a = *(const float4*)(v_in + (size_t)i * 96 + d * 32 + m0);
            const float4 b = *(const float4*)(v_in + (size_t)j * 96 + d * 32 + m0);
            vi[d][0] = a.x; vi[d][1] = a.y; vi[d][2] = a.z; vi[d][3] = a.w;
            vj[d][0] = b.x; vj[d][1] = b.y; vj[d][2] = b.z; vj[d][3] = b.w;
        }
        const float ux = us[e * 4 + 0], uy = us[e * 4 + 1], uz = us[e * 4 + 2];
        float aui[4], auj[4], aij[4], aii[4], ajj[4];
        #pragma unroll
        for (int mm = 0; mm < 4; mm++) {
            aui[mm] = ux * vi[0][mm] + uy * vi[1][mm] + uz * vi[2][mm];
            auj[mm] = ux * vj[0][mm] + uy * vj[1][mm] + uz * vj[2][mm];
            aij[mm] = vi[0][mm] * vj[0][mm] + vi[1][mm] * vj[1][mm] + vi[2][mm] * vj[2][mm];
            aii[mm] = vi[0][mm] * vi[0][mm] + vi[1][mm] * vi[1][mm] + vi[2][mm] * vi[2][mm];
            ajj[mm] = vj[0][mm] * vj[0][mm] + vj[1][mm] * vj[1][mm] + vj[2][mm] * vj[2][mm];
        }
        uint2 w;
        w.x = pack2bf(aui[0], aui[1]); w.y = pack2bf(aui[2], aui[3]);
        *(uint2*)&xs[e * XSTR + 32 + m0] = w;
        w.x = pack2bf(auj[0], auj[1]); w.y = pack2bf(auj[2], auj[3]);
        *(uint2*)&xs[e * XSTR + 64 + m0] = w;
        w.x = pack2bf(aij[0], aij[1]); w.y = pack2bf(aij[2], aij[3]);
        *(uint2*)&xs[e * XSTR + 96 + m0] = w;
        w.x = pack2bf(aii[0], aii[1]); w.y = pack2bf(aii[2], aii[3]);
        *(uint2*)&xs[e * XSTR + 128 + m0] = w;
        w.x = pack2bf(ajj[0], ajj[1]); w.y = pack2bf(ajj[2], ajj[3]);
        *(uint2*)&xs[e * XSTR + 160 + m0] = w;
    }

    // ---------------- e = [rbf|si|sj] @ Wrbf via MFMA -> xs cols [0,32) -------
    {
        const int rt = wid & 3;       // row-tile
        const int ct = wid >> 2;      // col-tile (0..1)
        f32x4 eacc = {0.f, 0.f, 0.f, 0.f};
        #pragma unroll
        for (int kb = 0; kb < 10; kb++) {
            bf16x8 bf = *(const bf16x8*)(pWrbf + ((size_t)(ct * 10 + kb) * 64 + lane) * 8);
            bf16x8 af;
            if (kb < 2) af = *(const bf16x8*)&h1[(rt * 16 + colf) * HSTR + kb * 32 + krow];
            else        af = *(const bf16x8*)&xs[(rt * 16 + colf) * XSTR + 128 + kb * 32 + krow];
            eacc = MFMA16(af, bf, eacc, 0, 0, 0);
        }
        #pragma unroll
        for (int r = 0; r < 4; r++) {
            const int row = rt * 16 + (lane >> 4) * 4 + r;
            xs[row * XSTR + ct * 16 + colf] = f2bf(eacc[r]);
        }
    }
    __syncthreads();   // (2) x tile complete; rbf consumed -> h1 region free

    // ---------------- fused GEMM1: h1_eq (->LDS) + h1_inv (->regs) ------------
    f32x4 ainv[4];
    {
        f32x4 aeq[4];
        const float bce = b1eq[wid * 16 + colf];
        const float bci = b1inv[wid * 16 + colf];
        #pragma unroll
        for (int rt = 0; rt < 4; rt++) {
            aeq[rt]  = (f32x4){bce, bce, bce, bce};
            ainv[rt] = (f32x4){bci, bci, bci, bci};
        }
        #pragma unroll
        for (int kb = 0; kb < 14; kb++) {
            bf16x8 af[4];
            #pragma unroll
            for (int rt = 0; rt < 4; rt++)
                af[rt] = *(const bf16x8*)&xs[(rt * 16 + colf) * XSTR + kb * 32 + krow];
            bf16x8 bi = *(const bf16x8*)(pW1inv + ((size_t)(wid * 14 + kb) * 64 + lane) * 8);
            #pragma unroll
            for (int rt = 0; rt < 4; rt++)
                ainv[rt] = MFMA16(af[rt], bi, ainv[rt], 0, 0, 0);
            if (!(eqSkip && kb >= 1 && kb < 6)) {
                bf16x8 be = *(const bf16x8*)(pW1eq + ((size_t)(wid * 14 + kb) * 64 + lane) * 8);
                #pragma unroll
                for (int rt = 0; rt < 4; rt++)
                    aeq[rt] = MFMA16(af[rt], be, aeq[rt], 0, 0, 0);
            }
        }
        #pragma unroll
        for (int rt = 0; rt < 4; rt++)
            #pragma unroll
            for (int r = 0; r < 4; r++) {
                const int row = rt * 16 + (lane >> 4) * 4 + r;
                h1[row * HSTR + wid * 16 + colf] = f2bf(silu_f(aeq[rt][r]));
            }
    }
    __syncthreads();   // (3) h1_eq ready; xs dead (gl/ml may alias after this)

    // ---------------- GEMM2-eq: g = h1_eq @ W2eq -> regs ----------------------
    f32x4 gacc[2];
    const int ct2 = wid & 3;
    const int rh  = wid >> 2;
    {
        gacc[0] = (f32x4){0.f, 0.f, 0.f, 0.f};
        gacc[1] = (f32x4){0.f, 0.f, 0.f, 0.f};
        #pragma unroll
        for (int kb = 0; kb < 4; kb++) {
            bf16x8 bf = *(const bf16x8*)(pW2eq + ((size_t)(ct2 * 4 + kb) * 64 + lane) * 8);
            #pragma unroll
            for (int q = 0; q < 2; q++) {
                bf16x8 af = *(const bf16x8*)&h1[((rh * 2 + q) * 16 + colf) * HSTR + kb * 32 + krow];
                gacc[q] = MFMA16(af, bf, gacc[q], 0, 0, 0);
            }
        }
    }
    __syncthreads();   // (4) h1_eq reads done

    // ---------------- write h1_inv + g ----------------------------------------
    {
        #pragma unroll
        for (int rt = 0; rt < 4; rt++)
            #pragma unroll
            for (int r = 0; r < 4; r++) {
                const int row = rt * 16 + (lane >> 4) * 4 + r;
                h1[row * HSTR + wid * 16 + colf] = f2bf(silu_f(ainv[rt][r]));
            }
        #pragma unroll
        for (int q = 0; q < 2; q++)
            #pragma unroll
            for (int r = 0; r < 4; r++) {
                const int row = (rh * 2 + q) * 16 + (lane >> 4) * 4 + r;
                gl[row * 68 + ct2 * 16 + colf] = gacc[q][r];
            }
    }
    __syncthreads();   // (5)

    // ---------------- GEMM2-inv: m = silu(h1_inv @ W2inv + b2) * cut ----------
    {
        f32x4 macc[4];
        const float bc = b2inv[wid * 16 + colf];
        #pragma unroll
        for (int rt = 0; rt < 4; rt++) macc[rt] = (f32x4){bc, bc, bc, bc};
        #pragma unroll
        for (int kb = 0; kb < 4; kb++) {
            bf16x8 bf = *(const bf16x8*)(pW2inv + ((size_t)(wid * 4 + kb) * 64 + lane) * 8);
            #pragma unroll
            for (int rt = 0; rt < 4; rt++) {
                bf16x8 af = *(const bf16x8*)&h1[(rt * 16 + colf) * HSTR + kb * 32 + krow];
                macc[rt] = MFMA16(af, bf, macc[rt], 0, 0, 0);
            }
        }
        #pragma unroll
        for (int rt = 0; rt < 4; rt++)
            #pragma unroll
            for (int r = 0; r < 4; r++) {
                const int row = rt * 16 + (lane >> 4) * 4 + r;
                ml[row * 132 + wid * 16 + colf] = silu_f(macc[rt][r]) * us[row * 4 + 3];
            }
    }
    __syncthreads();   // (6)

    // ---------------- sorted-run scan + scatter (two 32-edge halves) ----------
    {
        const int half = t >> 8;
        const int tl   = t & 255;
        if (tl < 224) {
            const int e0 = half * 32;
            if (tl < FDIM) {
                float acc = 0.f;
                for (int e = e0; e < e0 + 32; e++) {
                    acc += ml[e * 132 + tl];
                    if (e == e0 + 31 || iis[e + 1] != iis[e]) {
                        atomicAdd(&s_out[(size_t)iis[e] * FDIM + tl], acc);
                        acc = 0.f;
                    }
                }
            } else {
                const int col = tl - FDIM;          // 0..95
                const int d   = col >> 5;
                const int mm  = col & 31;
                float acc = 0.f;
                for (int e = e0; e < e0 + 32; e++) {
                    const float g0  = gl[e * 68 + mm];
                    const float g1  = gl[e * 68 + 32 + mm];
                    const float vjv = v_in[(size_t)jjs[e] * 96 + col];
                    acc = fmaf(us[e * 4 + 3], fmaf(g0, us[e * 4 + d], g1 * vjv), acc);
                    if (e == e0 + 31 || iis[e + 1] != iis[e]) {
                        atomicAdd(&v_out[(size_t)iis[e] * 96 + col], acc);
                        acc = 0.f;
                    }
                }
            }
        }
    }
}

// ---------------------------------------------------------------------------
// MFMA node update: s_out = s_in + silu(silu([s,s@Wemb]@W1u+b1u)@W2u+b2u)
// 32 atoms/block, 256 threads (4 waves). Also emits bf16 mirror.
// ---------------------------------------------------------------------------
__global__ __launch_bounds__(256, 4)
void node_kernel(const float* __restrict__ s_in,
                 const ushort_t* __restrict__ pWemb,
                 const ushort_t* __restrict__ pW1u,
                 const float* __restrict__ b1u,
                 const ushort_t* __restrict__ pW2u,
                 const float* __restrict__ b2u,
                 float* __restrict__ s_out,
                 ushort_t* __restrict__ sbf_out)
{
    __shared__ ushort_t ss[AT * HSTR];
    __shared__ ushort_t fe[AT * HSTR];
    __shared__ ushort_t t1[AT * HSTR];
    const int t    = threadIdx.x;
    const int a0   = blockIdx.x * AT;
    const int lane = t & 63;
    const int wid  = t >> 6;
    const int colf = lane & 15;
    const int krow = (lane >> 4) * 8;

    // stage s -> bf16 LDS
    {
        const int a = t >> 3, l = t & 7;
        const float4* sr = (const float4*)(s_in + (size_t)(a0 + a) * FDIM);
        float4 q0 = sr[l * 4 + 0], q1 = sr[l * 4 + 1], q2 = sr[l * 4 + 2], q3 = sr[l * 4 + 3];
        *(uint4*)&ss[a * HSTR + l * 16]     = cvt8(q0, q1);
        *(uint4*)&ss[a * HSTR + l * 16 + 8] = cvt8(q2, q3);
    }
    __syncthreads();

    // femb = s @ Wemb -> fe (bf16)
    #pragma unroll
    for (int ci = 0; ci < 2; ci++) {
        const int ct = wid * 2 + ci;
        f32x4 acc[2];
        acc[0] = (f32x4){0.f, 0.f, 0.f, 0.f};
        acc[1] = (f32x4){0.f, 0.f, 0.f, 0.f};
        #pragma unroll
        for (int kb = 0; kb < 4; kb++) {
            bf16x8 bf = *(const bf16x8*)(pWemb + ((size_t)(ct * 4 + kb) * 64 + lane) * 8);
            #pragma unroll
            for (int rt = 0; rt < 2; rt++) {
                bf16x8 af = *(const bf16x8*)&ss[(rt * 16 + colf) * HSTR + kb * 32 + krow];
                acc[rt] = MFMA16(af, bf, acc[rt], 0, 0, 0);
            }
        }
        #pragma unroll
        for (int rt = 0; rt < 2; rt++)
            #pragma unroll
            for (int r = 0; r < 4; r++) {
                const int row = rt * 16 + (lane >> 4) * 4 + r;
                fe[row * HSTR + ct * 16 + colf] = f2bf(acc[rt][r]);
            }
    }
    __syncthreads();

    // t1 = silu([s,femb] @ W1u + b1u)
    #pragma unroll
    for (int ci = 0; ci < 2; ci++) {
        const int ct = wid * 2 + ci;
        const float bc = b1u[ct * 16 + colf];
        f32x4 acc[2];
        acc[0] = (f32x4){bc, bc, bc, bc};
        acc[1] = (f32x4){bc, bc, bc, bc};
        #pragma unroll
        for (int kb = 0; kb < 8; kb++) {
            bf16x8 bf = *(const bf16x8*)(pW1u + ((size_t)(ct * 8 + kb) * 64 + lane) * 8);
            #pragma unroll
            for (int rt = 0; rt < 2; rt++) {
                bf16x8 af;
                if (kb < 4) af = *(const bf16x8*)&ss[(rt * 16 + colf) * HSTR + kb * 32 + krow];
                else        af = *(const bf16x8*)&fe[(rt * 16 + colf) * HSTR + (kb - 4) * 32 + krow];
                acc[rt] = MFMA16(af, bf, acc[rt], 0, 0, 0);
            }
        }
        #pragma unroll
        for (int rt = 0; rt < 2; rt++)
            #pragma unroll
            for (int r = 0; r < 4; r++) {
                const int row = rt * 16 + (lane >> 4) * 4 + r;
                t1[row * HSTR + ct * 16 + colf] = f2bf(silu_f(acc[rt][r]));
            }
    }
    __syncthreads();

    // s_out = s_in + silu(t1 @ W2u + b2u); also bf16 mirror
    #pragma unroll
    for (int ci = 0; ci < 2; ci++) {
        const int ct = wid * 2 + ci;
        const float bc = b2u[ct * 16 + colf];
        f32x4 acc[2];
        acc[0] = (f32x4){bc, bc, bc, bc};
        acc[1] = (f32x4){bc, bc, bc, bc};
        #pragma unroll
        for (int kb = 0; kb < 4; kb++) {
            bf16x8 bf = *(const bf16x8*)(pW2u + ((size_t)(ct * 4 + kb) * 64 + lane) * 8);
            #pragma unroll
            for (int rt = 0; rt < 2; rt++) {
                bf16x8 af = *(const bf16x8*)&t1[(rt * 16 + colf) * HSTR + kb * 32 + krow];
                acc[rt] = MFMA16(af, bf, acc[rt], 0, 0, 0);
            }
        }
        #pragma unroll
        for (int rt = 0; rt < 2; rt++)
            #pragma unroll
            for (int r = 0; r < 4; r++) {
                const int row = rt * 16 + (lane >> 4) * 4 + r;
                const size_t off = (size_t)(a0 + row) * FDIM + ct * 16 + colf;
                const float o = s_in[off] + silu_f(acc[rt][r]);
                s_out[off] = o;
                sbf_out[off] = f2bf(o);
            }
    }
}

// ---------------------------------------------------------------------------
__global__ void copyf4(float4* __restrict__ dst, const float4* __restrict__ src, int n4) {
    int i = blockIdx.x * blockDim.x + threadIdx.x;
    const int stride = gridDim.x * blockDim.x;
    for (; i < n4; i += stride) dst[i] = src[i];
}

__global__ void zerof4(float4* __restrict__ dst, int n4) {
    int i = blockIdx.x * blockDim.x + threadIdx.x;
    const int stride = gridDim.x * blockDim.x;
    const float4 z = make_float4(0.f, 0.f, 0.f, 0.f);
    for (; i < n4; i += stride) dst[i] = z;
}

__global__ void cvt_bf(const float* __restrict__ in, ushort_t* __restrict__ out, int n8) {
    int i = blockIdx.x * blockDim.x + threadIdx.x;
    if (i < n8) {
        const float4* s = (const float4*)(in + (size_t)i * 8);
        *(uint4*)(out + (size_t)i * 8) = cvt8(s[0], s[1]);
    }
}

// ---------------------------------------------------------------------------
extern "C" void kernel_launch(void* const* d_in, const int* in_sizes, int n_in,
                              void* d_out, int out_size, void* d_ws, size_t ws_size,
                              hipStream_t stream) {
    (void)in_sizes; (void)n_in; (void)out_size; (void)ws_size;

    const float* features = (const float*)d_in[0];
    const float* dists    = (const float*)d_in[1];
    const float* vecs     = (const float*)d_in[2];
    const float* cuts     = (const float*)d_in[3];
    const float* rbfs     = (const float*)d_in[4];
    const int*   idx_i    = (const int*)d_in[5];
    const int*   idx_j    = (const int*)d_in[6];
    const float* Wrbf     = (const float*)d_in[7];
    const float* Wemb     = (const float*)d_in[8];
    const float* eq0_W1   = (const float*)d_in[9];
    const float* eq0_b1   = (const float*)d_in[10];
    const float* eq0_W2   = (const float*)d_in[11];
    const float* eq1_W1   = (const float*)d_in[12];
    const float* eq1_b1   = (const float*)d_in[13];
    const float* eq1_W2   = (const float*)d_in[14];
    const float* inv_W1   = (const float*)d_in[15];
    const float* inv_b1   = (const float*)d_in[16];
    const float* inv_W2   = (const float*)d_in[17];
    const float* inv_b2   = (const float*)d_in[18];
    const float* upd_W1   = (const float*)d_in[19];
    const float* upd_b1   = (const float*)d_in[20];
    const float* upd_W2   = (const float*)d_in[21];
    const float* upd_b2   = (const float*)d_in[22];

    float*    sA  = (float*)d_ws;                       // NA*128
    float*    sB  = sA + (size_t)NA * FDIM;             // NA*128
    float*    vA  = sB + (size_t)NA * FDIM;             // NA*96
    float*    vB  = vA + (size_t)NA * 96;               // NA*96
    ushort_t* sbf = (ushort_t*)(vB + (size_t)NA * 96);  // NA*128 ushort
    ushort_t* pwb = sbf + (size_t)NA * FDIM;            // PK_TOTAL*8 ushort

    float* s_final = (float*)d_out;
    float* v_final = s_final + (size_t)NA * FDIM;

    const int SN4 = NA * FDIM / 4;
    const int VN4 = NA * 96 / 4;

    pack_all<<<(PK_TOTAL + 255) / 256, 256, 0, stream>>>(
        eq0_W1, eq1_W1, inv_W1, eq0_W2, eq1_W2, inv_W2, Wrbf, Wemb, upd_W1, upd_W2, pwb);
    cvt_bf<<<(NA * FDIM / 8 + 255) / 256, 256, 0, stream>>>(features, sbf, NA * FDIM / 8);
    copyf4<<<1024, 256, 0, stream>>>((float4*)sB, (const float4*)features, SN4);
    zerof4<<<1024, 256, 0, stream>>>((float4*)vA, VN4);
    zerof4<<<1024, 256, 0, stream>>>((float4*)vB, VN4);

    // ---- block 0: edge reads (sbf, vA) -> accum (sB, vB); node: sB -> sA,sbf --
    edge_kernel<<<PE / ET, 512, 0, stream>>>(
        rbfs, dists, vecs, cuts, idx_i, idx_j, sbf, vA,
        pwb + (size_t)PK_WRBF * 8,
        pwb + (size_t)PK_W1EQ0 * 8, eq0_b1, pwb + (size_t)PK_W2EQ0 * 8,
        pwb + (size_t)PK_W1INV0 * 8, inv_b1, pwb + (size_t)PK_W2INV0 * 8, inv_b2,
        sB, vB, 1);
    node_kernel<<<NA / AT, 256, 0, stream>>>(
        sB, pwb + (size_t)PK_WEMB * 8, pwb + (size_t)PK_W1U0 * 8, upd_b1,
        pwb + (size_t)PK_W2U0 * 8, upd_b2, sA, sbf);

    // ---- block 1: edge reads (sbf, vB) -> accum (sB, vA); node: sB -> d_out ---
    copyf4<<<1024, 256, 0, stream>>>((float4*)sB, (const float4*)sA, SN4);
    copyf4<<<1024, 256, 0, stream>>>((float4*)vA, (const float4*)vB, VN4);
    edge_kernel<<<PE / ET, 512, 0, stream>>>(
        rbfs, dists, vecs, cuts, idx_i, idx_j, sbf, vB,
        pwb + (size_t)PK_WRBF * 8,
        pwb + (size_t)PK_W1EQ1 * 8, eq1_b1, pwb + (size_t)PK_W2EQ1 * 8,
        pwb + (size_t)PK_W1INV1 * 8, inv_b1 + FDIM, pwb + (size_t)PK_W2INV1 * 8, inv_b2 + FDIM,
        sB, vA, 0);
    node_kernel<<<NA / AT, 256, 0, stream>>>(
        sB, pwb + (size_t)PK_WEMB * 8, pwb + (size_t)PK_W1U1 * 8, upd_b1 + FDIM,
        pwb + (size_t)PK_W2U1 * 8, upd_b2 + FDIM, s_final, sbf);

    copyf4<<<1024, 256, 0, stream>>>((float4*)v_final, (const float4*)vA, VN4);
}